// Round 7
// baseline (12790.071 us; speedup 1.0000x reference)
//
#include <hip/hip_runtime.h>

// Hierarchical RNN — tagged-dataflow persistent kernel, v7.
// vs v6: forward sync via per-column tags embedded next to the data
// (producer: payload stores -> fence -> tag store; consumer: spin on its
// own 32 tag words -> load -> FMA). No pre-compute barrier, no poll waves,
// no group-wide flag convoy on the forward path. Flags remain only as
// WAR guards (slack >= 3 steps, normally non-blocking).

#define TSTEPS 512
#define BATCH  128
#define DMOD   3
#define NH     512
#define CCLS   2

#define BT     32
#define NT     8
#define MSEG   8
#define NTHR   256
#define NBLK   768
#define RING   4
#define OUT2   (DMOD * BATCH * NH)

typedef unsigned long long u64;
typedef unsigned int u32;
typedef float v2f __attribute__((ext_vector_type(2)));

__device__ __forceinline__ float bflo(u32 u) { return __uint_as_float(u << 16); }
__device__ __forceinline__ float bfhi(u32 u) { return __uint_as_float(u & 0xffff0000u); }
__device__ __forceinline__ unsigned short f2bf(float x) {
    u32 u = __float_as_uint(x);
    return (unsigned short)((u + 0x7fffu + ((u >> 16) & 1u)) >> 16);
}
__device__ __forceinline__ u64 pack4bf(float a, float b, float c, float d) {
    u32 lo = (u32)f2bf(a) | ((u32)f2bf(b) << 16);
    u32 hi = (u32)f2bf(c) | ((u32)f2bf(d) << 16);
    return (u64)lo | ((u64)hi << 32);
}
__device__ __forceinline__ float lrelu(float x) { return fmaxf(x, 0.01f * x); }

__device__ __forceinline__ u64 ld_h(const u64* p) {
    return __hip_atomic_load(p, __ATOMIC_RELAXED, __HIP_MEMORY_SCOPE_AGENT);
}
__device__ __forceinline__ void st_h(u64* p, u64 v) {
    __hip_atomic_store(p, v, __ATOMIC_RELAXED, __HIP_MEMORY_SCOPE_AGENT);
}
__device__ __forceinline__ u32 ld_tag(const u32* p) {
    return __hip_atomic_load(p, __ATOMIC_RELAXED, __HIP_MEMORY_SCOPE_AGENT);
}
__device__ __forceinline__ void st_tag(u32* p, u32 v) {
    __hip_atomic_store(p, v, __ATOMIC_RELAXED, __HIP_MEMORY_SCOPE_AGENT);
}
__device__ __forceinline__ int ld_slot(const int* p) {
    return __hip_atomic_load(p, __ATOMIC_RELAXED, __HIP_MEMORY_SCOPE_AGENT);
}
__device__ __forceinline__ void st_slot(int* p, int v) {
    __hip_atomic_store(p, v, __ATOMIC_RELAXED, __HIP_MEMORY_SCOPE_AGENT);
}

#define PK4(H, WP, OFF) { v2f h2_ = {(H), (H)}; \
    acc0 += h2_ * WP[(OFF) + 0]; acc1 += h2_ * WP[(OFF) + 1]; \
    acc2 += h2_ * WP[(OFF) + 2]; acc3 += h2_ * WP[(OFF) + 3]; }

#define PKU64(U, WP) { \
    PK4(bflo((u32)(U)), WP, 0) \
    PK4(bfhi((u32)(U)), WP, 4) \
    PK4(bflo((u32)((U) >> 32)), WP, 8) \
    PK4(bfhi((u32)((U) >> 32)), WP, 12) }

__global__ __launch_bounds__(NTHR, 3)
void rnn_tagged(const float* __restrict__ data,
                const float* __restrict__ h0,
                const float* __restrict__ W_in,
                const float* __restrict__ b_in,
                const float* __restrict__ W_hh,
                const float* __restrict__ b_hh,
                const float* __restrict__ W_ff,
                const float* __restrict__ b_ff,
                const float* __restrict__ taus,
                const float* __restrict__ W_fc,
                const float* __restrict__ b_fc,
                float* __restrict__ out,
                int* __restrict__ wsI)
{
    __shared__ float4 s_whh[NH * 2];            // 16 KB
    __shared__ float4 s_wff[NH * 2];            // 16 KB
    __shared__ float4 s_red[MSEG][BT][2];       // 8 KB

    const int tid = threadIdx.x;
    const int blk = blockIdx.x;
    const int d   = blk >> 8;
    const int rem = blk & 255;
    const int bt  = rem >> 6;
    const int nt  = rem & 63;
    const int b0  = bt * BT;
    const int n0  = nt * NT;
    const int g   = d * 4 + bt;

    // ws layout: flags[12][64] @0; tags[RING][12][128] @16384; hb @65536
    int* flags = wsI;
    u32* tags  = (u32*)((char*)wsI + 16384);
    u64* hbq   = (u64*)((char*)wsI + 65536);

    // ---- stage weight tiles (transposed [m][n_local]) into LDS ----
    {
        float* sw = (float*)s_whh;
        const float* gw = W_hh + (size_t)d * NH * NH;
        for (int idx = tid; idx < NH * NT; idx += NTHR) {
            int nl = idx >> 9;
            int m  = idx & (NH - 1);
            float v = gw[(size_t)(n0 + nl) * NH + m];
            if (n0 + nl == m) v = 0.0f;
            sw[m * NT + nl] = v;
        }
        if (d > 0) {
            float* sf = (float*)s_wff;
            const float* gf = W_ff + (size_t)(d - 1) * NH * NH;
            for (int idx = tid; idx < NH * NT; idx += NTHR) {
                int nl = idx >> 9;
                int m  = idx & (NH - 1);
                sf[m * NT + nl] = gf[(size_t)(n0 + nl) * NH + m];
            }
        }
    }

    const int mseg = tid >> 5;
    const int bb   = tid & 31;
    const int b    = b0 + bb;
    const int m0   = mseg * (NH / MSEG);
    const int mg0  = m0 >> 2;                   // = mseg*16

    int* fgo    = flags + g * 64;                               // own group (WAR)
    int* fup    = (d < DMOD - 1) ? (flags + (g + 4) * 64) : nullptr;
    int* myflag = flags + g * 64 + nt;

    // finalizer constants (wave 0: tid<64 -> (fb, nh): 4 n each)
    const int fb = tid >> 1;
    const int nh = tid & 1;
    float winp[4], cbias[4], al[4], itau[4];
    u64 prev = 0;
    if (tid < 64) {
#pragma unroll
        for (int j = 0; j < 4; ++j) {
            int n = n0 + nh * 4 + j;
            winp[j] = W_in[d * NH + n];
            float cb = b_hh[d * NH + n] + b_in[d * NH + n];
            if (d > 0) cb += b_ff[(d - 1) * NH + n];
            cbias[j] = cb;
            float tc = fmaxf(taus[d * NH + n], 1.0f);
            itau[j]  = 1.0f / tc;
            al[j]    = 1.0f - itau[j];
        }
    }

    for (int t = 0; t < TSTEPS; ++t) {
        // xs prefetch (cached load, used in finalize)
        float xs = 0.0f;
        if (tid < 64) xs = data[t * BATCH + (b0 + fb)];

        const bool needO = (t > 0);
        const bool needF = (d > 0);

        // ---- per-thread tag spin: own epoch t-1 (value t), ff epoch t (value t+1)
        const u32* tgo = tags + (((size_t)((t - 1) & 3) * 12 + g) * 128) + mseg * 16;
        const u32* tgf = tags + (((size_t)(t & 3) * 12 + (g - 4)) * 128) + mseg * 16;
        const u32 eo = (u32)t, ef = (u32)(t + 1);
        if (needO || needF) {
            while (1) {
                bool ok = true;
                if (needO) {
#pragma unroll
                    for (int i = 0; i < 16; ++i) ok &= (ld_tag(tgo + i) == eo);
                }
                if (needF) {
#pragma unroll
                    for (int i = 0; i < 16; ++i) ok &= (ld_tag(tgf + i) == ef);
                }
                if (ok) break;
                __builtin_amdgcn_s_sleep(2);
            }
            asm volatile("" ::: "memory");   // don't hoist payload loads above spin
        }

        // ---- matmul ----
        v2f acc0 = {0, 0}, acc1 = {0, 0}, acc2 = {0, 0}, acc3 = {0, 0};

        if (t == 0) {
            const float4* hr = (const float4*)(h0 + (size_t)(d * BATCH + b) * NH);
            float4 hv[16];
#pragma unroll
            for (int i = 0; i < 16; ++i) hv[i] = hr[mg0 + i];
            u64 gu[16];
            if (needF) {
                const u64* hg = hbq + (((size_t)(0 * 12) + (g - 4)) << 12);
#pragma unroll
                for (int i = 0; i < 16; ++i) gu[i] = ld_h(hg + (mg0 + i) * 32 + bb);
            }
#pragma unroll
            for (int i = 0; i < 16; ++i) {
                const v2f* wp = (const v2f*)(s_whh + (m0 + i * 4) * 2);
                PK4(hv[i].x, wp, 0)  PK4(hv[i].y, wp, 4)
                PK4(hv[i].z, wp, 8)  PK4(hv[i].w, wp, 12)
            }
            if (needF) {
#pragma unroll
                for (int i = 0; i < 16; ++i) {
                    const v2f* wp = (const v2f*)(s_wff + (m0 + i * 4) * 2);
                    PKU64(gu[i], wp)
                }
            }
        } else {
            const u64* hr = hbq + (((size_t)((t - 1) & 3) * 12 + g) << 12);
            u64 hu[16];
#pragma unroll
            for (int i = 0; i < 16; ++i) hu[i] = ld_h(hr + (mg0 + i) * 32 + bb);
            u64 gu[16];
            if (needF) {
                const u64* hg = hbq + (((size_t)(t & 3) * 12 + (g - 4)) << 12);
#pragma unroll
                for (int i = 0; i < 16; ++i) gu[i] = ld_h(hg + (mg0 + i) * 32 + bb);
            }
#pragma unroll
            for (int i = 0; i < 16; ++i) {
                const v2f* wp = (const v2f*)(s_whh + (m0 + i * 4) * 2);
                PKU64(hu[i], wp)
            }
            if (needF) {
#pragma unroll
                for (int i = 0; i < 16; ++i) {
                    const v2f* wp = (const v2f*)(s_wff + (m0 + i * 4) * 2);
                    PKU64(gu[i], wp)
                }
            }
        }

        s_red[mseg][bb][0] = make_float4(acc0.x, acc0.y, acc1.x, acc1.y);
        s_red[mseg][bb][1] = make_float4(acc2.x, acc2.y, acc3.x, acc3.y);
        __syncthreads();                       // B1: s_red ready

        float4 s = make_float4(0.f, 0.f, 0.f, 0.f);
        if (tid < 64) {
            s = s_red[0][fb][nh];
#pragma unroll
            for (int ms = 1; ms < MSEG; ++ms) {
                float4 r = s_red[ms][fb][nh];
                s.x += r.x; s.y += r.y; s.z += r.z; s.w += r.w;
            }
        }
        __syncthreads();                       // B2: s_red free; waves 1-3 move on

        if (tid < 64) {
            if (tid == 0) st_slot(myflag, t + 1);   // reads for step t complete

            float h0f, h1f, h2f, h3f;
            if (t == 0) {
                float4 v = *(const float4*)(h0 + (size_t)(d * BATCH + b0 + fb) * NH
                                            + n0 + nh * 4);
                h0f = v.x; h1f = v.y; h2f = v.z; h3f = v.w;
            } else {
                h0f = bflo((u32)prev);         h1f = bfhi((u32)prev);
                h2f = bflo((u32)(prev >> 32)); h3f = bfhi((u32)(prev >> 32));
            }
            float p0 = s.x + cbias[0] + xs * winp[0];
            float p1 = s.y + cbias[1] + xs * winp[1];
            float p2 = s.z + cbias[2] + xs * winp[2];
            float p3 = s.w + cbias[3] + xs * winp[3];
            float n0v = al[0] * h0f + lrelu(p0) * itau[0];
            float n1v = al[1] * h1f + lrelu(p1) * itau[1];
            float n2v = al[2] * h2f + lrelu(p2) * itau[2];
            float n3v = al[3] * h3f + lrelu(p3) * itau[3];
            u64 pk = pack4bf(n0v, n1v, n2v, n3v);

            // WAR guards (ring slack >= 3 steps; normally instant)
            if (t >= 3) {
                while (!__all(ld_slot(fgo + tid) >= t - 2)) __builtin_amdgcn_s_sleep(1);
            }
            if (d < DMOD - 1 && t >= 4) {
                while (!__all(ld_slot(fup + tid) >= t - 3)) __builtin_amdgcn_s_sleep(1);
            }

            u64* dst = hbq + (((size_t)(t & 3) * 12 + g) << 12)
                     + (size_t)(nt * 2 + nh) * 32 + fb;
            st_h(dst, pk);
            prev = pk;
            if (t == TSTEPS - 1) {
                *(float4*)(out + (size_t)(d * BATCH + b0 + fb) * NH + n0 + nh * 4)
                    = make_float4(n0v, n1v, n2v, n3v);
            }
            __threadfence_block();             // payload acked before tag
            if (tid < 2) {
                u32* tg = tags + (((size_t)(t & 3) * 12 + g) * 128);
                st_tag(tg + nt * 2 + tid, (u32)(t + 1));
            }
        }
    }

    // ---- readout: wait for final epoch tags, then compute heads ----
    {
        const u32* tf = tags + (((size_t)((TSTEPS - 1) & 3) * 12 + g) * 128);
        if (tid < 128) {
            while (ld_tag(tf + tid) != (u32)TSTEPS) __builtin_amdgcn_s_sleep(2);
        }
        __syncthreads();
        asm volatile("" ::: "memory");
    }
    if (nt < CCLS && tid < BT) {
        const int c   = nt;
        const int row = b0 + tid;
        const u64* hf = hbq + (((size_t)((TSTEPS - 1) & 3) * 12 + g) << 12);
        const float4* wf = (const float4*)(W_fc + (size_t)(d * CCLS + c) * NH);
        float sacc = b_fc[d * CCLS + c];
        for (int q = 0; q < NH / 4; ++q) {
            u64 u = ld_h(hf + (size_t)q * 32 + tid);
            float4 w = wf[q];
            sacc += bflo((u32)u) * w.x + bfhi((u32)u) * w.y
                  + bflo((u32)(u >> 32)) * w.z + bfhi((u32)(u >> 32)) * w.w;
        }
        out[OUT2 + (size_t)(d * BATCH + row) * CCLS + c] = sacc;
    }
}

extern "C" void kernel_launch(void* const* d_in, const int* in_sizes, int n_in,
                              void* d_out, int out_size, void* d_ws, size_t ws_size,
                              hipStream_t stream) {
    const float* data = (const float*)d_in[0];
    const float* h0   = (const float*)d_in[1];
    const float* W_in = (const float*)d_in[2];
    const float* b_in = (const float*)d_in[3];
    const float* W_hh = (const float*)d_in[4];
    const float* b_hh = (const float*)d_in[5];
    const float* W_ff = (const float*)d_in[6];
    const float* b_ff = (const float*)d_in[7];
    const float* taus = (const float*)d_in[8];
    const float* W_fc = (const float*)d_in[9];
    const float* b_fc = (const float*)d_in[10];

    // no init: flags poison 0xAA = negative ("not done"); tag poison != any
    // expected value 1..512. Harness re-poisons ws before every launch.
    hipLaunchKernelGGL(rnn_tagged, dim3(NBLK), dim3(NTHR), 0, stream,
                       data, h0, W_in, b_in, W_hh, b_hh, W_ff, b_ff,
                       taus, W_fc, b_fc, (float*)d_out, (int*)d_ws);
}

// Round 8
// 8514.581 us; speedup vs baseline: 1.5021x; 1.5021x over previous
//
#include <hip/hip_runtime.h>

// Hierarchical RNN — dataflow persistent kernel, v8.
// Base v6 + (1) per-producer tags: each wave spins on exactly its 16 own +
// 16 ff producer tag words (2 cache lines, lanes 0-31, one __all);
// (2) no pre-matmul barrier: waves start compute when THEIR slice is ready;
// single __syncthreads per step, s_red double-buffered by parity;
// (3) WAR read-flags with 3-4 step ring slack, store-only, polled by the
// finalize wave (normally instant).

#define TSTEPS 512
#define BATCH  128
#define DMOD   3
#define NH     512
#define CCLS   2

#define BT     32
#define NT     8
#define MSEG   8
#define NTHR   256
#define NBLK   768
#define OUT2   (DMOD * BATCH * NH)

typedef unsigned long long u64;
typedef unsigned int u32;
typedef float v2f __attribute__((ext_vector_type(2)));

__device__ __forceinline__ float bflo(u32 u) { return __uint_as_float(u << 16); }
__device__ __forceinline__ float bfhi(u32 u) { return __uint_as_float(u & 0xffff0000u); }
__device__ __forceinline__ unsigned short f2bf(float x) {
    u32 u = __float_as_uint(x);
    return (unsigned short)((u + 0x7fffu + ((u >> 16) & 1u)) >> 16);
}
__device__ __forceinline__ u64 pack4bf(float a, float b, float c, float d) {
    u32 lo = (u32)f2bf(a) | ((u32)f2bf(b) << 16);
    u32 hi = (u32)f2bf(c) | ((u32)f2bf(d) << 16);
    return (u64)lo | ((u64)hi << 32);
}
__device__ __forceinline__ float lrelu(float x) { return fmaxf(x, 0.01f * x); }

__device__ __forceinline__ u64 ld_h(const u64* p) {
    return __hip_atomic_load(p, __ATOMIC_RELAXED, __HIP_MEMORY_SCOPE_AGENT);
}
__device__ __forceinline__ void st_h(u64* p, u64 v) {
    __hip_atomic_store(p, v, __ATOMIC_RELAXED, __HIP_MEMORY_SCOPE_AGENT);
}
__device__ __forceinline__ u32 ld_tag(const u32* p) {
    return __hip_atomic_load(p, __ATOMIC_RELAXED, __HIP_MEMORY_SCOPE_AGENT);
}
__device__ __forceinline__ void st_tag(u32* p, u32 v) {
    __hip_atomic_store(p, v, __ATOMIC_RELAXED, __HIP_MEMORY_SCOPE_AGENT);
}
__device__ __forceinline__ int ld_slot(const int* p) {
    return __hip_atomic_load(p, __ATOMIC_RELAXED, __HIP_MEMORY_SCOPE_AGENT);
}
__device__ __forceinline__ void st_slot(int* p, int v) {
    __hip_atomic_store(p, v, __ATOMIC_RELAXED, __HIP_MEMORY_SCOPE_AGENT);
}

#define PK4(H, WP, OFF) { v2f h2_ = {(H), (H)}; \
    acc0 += h2_ * WP[(OFF) + 0]; acc1 += h2_ * WP[(OFF) + 1]; \
    acc2 += h2_ * WP[(OFF) + 2]; acc3 += h2_ * WP[(OFF) + 3]; }

#define PKU64(U, WP) { \
    PK4(bflo((u32)(U)), WP, 0) \
    PK4(bfhi((u32)(U)), WP, 4) \
    PK4(bflo((u32)((U) >> 32)), WP, 8) \
    PK4(bfhi((u32)((U) >> 32)), WP, 12) }

__global__ __launch_bounds__(NTHR, 3)
void rnn_v8(const float* __restrict__ data,
            const float* __restrict__ h0,
            const float* __restrict__ W_in,
            const float* __restrict__ b_in,
            const float* __restrict__ W_hh,
            const float* __restrict__ b_hh,
            const float* __restrict__ W_ff,
            const float* __restrict__ b_ff,
            const float* __restrict__ taus,
            const float* __restrict__ W_fc,
            const float* __restrict__ b_fc,
            float* __restrict__ out,
            int* __restrict__ wsI)
{
    __shared__ float4 s_whh[NH * 2];              // 16 KB
    __shared__ float4 s_wff[NH * 2];              // 16 KB
    __shared__ float4 s_red[2][MSEG][BT][2];      // 16 KB (double-buffered)

    const int tid = threadIdx.x;
    const int blk = blockIdx.x;
    const int d   = blk >> 8;
    const int rem = blk & 255;
    const int bt  = rem >> 6;
    const int nt  = rem & 63;
    const int b0  = bt * BT;
    const int n0  = nt * NT;
    const int g   = d * 4 + bt;

    // ws: tags[4][12][64] u32 @0 (12 KB); rdflags[12][64] int @16384; hb @65536
    u32* tags = (u32*)wsI;
    int* rdfl = wsI + 4096;
    u64* hbq  = (u64*)((char*)wsI + 65536);

    // ---- stage weight tiles (transposed [m][n_local]) into LDS ----
    {
        float* sw = (float*)s_whh;
        const float* gw = W_hh + (size_t)d * NH * NH;
        for (int idx = tid; idx < NH * NT; idx += NTHR) {
            int nl = idx >> 9;
            int m  = idx & (NH - 1);
            float v = gw[(size_t)(n0 + nl) * NH + m];
            if (n0 + nl == m) v = 0.0f;
            sw[m * NT + nl] = v;
        }
        if (d > 0) {
            float* sf = (float*)s_wff;
            const float* gf = W_ff + (size_t)(d - 1) * NH * NH;
            for (int idx = tid; idx < NH * NT; idx += NTHR) {
                int nl = idx >> 9;
                int m  = idx & (NH - 1);
                sf[m * NT + nl] = gf[(size_t)(n0 + nl) * NH + m];
            }
        }
    }
    __syncthreads();   // weights staged before any wave computes

    const int wave = tid >> 6;
    const int lane = tid & 63;
    const int mseg = tid >> 5;
    const int bb   = tid & 31;
    const int b    = b0 + bb;
    const int m0   = mseg * (NH / MSEG);
    const int mg0  = m0 >> 2;

    // spin roles: lanes 0-15 own producers, 16-31 ff producers (this wave's slice)
    const int  sidx    = (wave << 4) + (lane & 15);       // producer nt in slice
    const bool ownLane = (lane < 16);
    const bool ffLane  = (lane >= 16 && lane < 32 && d > 0);

    // finalizer constants (wave 0: tid<64 -> (fb, nh): 4 n each)
    const int fb = tid >> 1;
    const int nh = tid & 1;
    float winp[4], cbias[4], al[4], itau[4];
    u64 prev = 0;
    if (tid < 64) {
#pragma unroll
        for (int j = 0; j < 4; ++j) {
            int n = n0 + nh * 4 + j;
            winp[j] = W_in[d * NH + n];
            float cb = b_hh[d * NH + n] + b_in[d * NH + n];
            if (d > 0) cb += b_ff[(d - 1) * NH + n];
            cbias[j] = cb;
            float tc = fmaxf(taus[d * NH + n], 1.0f);
            itau[j]  = 1.0f / tc;
            al[j]    = 1.0f - itau[j];
        }
    }

    for (int t = 0; t < TSTEPS; ++t) {
        float xs = 0.0f;
        if (tid < 64) xs = data[t * BATCH + (b0 + fb)];

        // ---- per-wave slice spin: 2 cache lines, one __all ----
        const bool needOwn = ownLane && (t > 0);
        const bool needFf  = ffLane;
        if ((t > 0) || (d > 0)) {
            const u32* aown = tags + (size_t)((t - 1) & 3) * 768 + g * 64 + sidx;
            const u32* aff  = tags + (size_t)(t & 3) * 768 + (g - 4) * 64 + sidx;
            while (1) {
                bool ok = true;
                if (needOwn)     ok = (ld_tag(aown) == (u32)t);
                else if (needFf) ok = (ld_tag(aff)  == (u32)(t + 1));
                if (__all(ok)) break;
                __builtin_amdgcn_s_sleep(1);
            }
            asm volatile("" ::: "memory");
        }

        // ---- matmul (slice is ready) ----
        v2f acc0 = {0, 0}, acc1 = {0, 0}, acc2 = {0, 0}, acc3 = {0, 0};

        if (t == 0) {
            const float4* hr = (const float4*)(h0 + (size_t)(d * BATCH + b) * NH);
            float4 hv[16];
#pragma unroll
            for (int i = 0; i < 16; ++i) hv[i] = hr[mg0 + i];
            u64 gu[16];
            if (d > 0) {
                const u64* hg = hbq + ((size_t)(g - 4) << 12);
#pragma unroll
                for (int i = 0; i < 16; ++i) gu[i] = ld_h(hg + (mg0 + i) * 32 + bb);
            }
#pragma unroll
            for (int i = 0; i < 16; ++i) {
                const v2f* wp = (const v2f*)(s_whh + (m0 + i * 4) * 2);
                PK4(hv[i].x, wp, 0)  PK4(hv[i].y, wp, 4)
                PK4(hv[i].z, wp, 8)  PK4(hv[i].w, wp, 12)
            }
            if (d > 0) {
#pragma unroll
                for (int i = 0; i < 16; ++i) {
                    const v2f* wp = (const v2f*)(s_wff + (m0 + i * 4) * 2);
                    PKU64(gu[i], wp)
                }
            }
        } else {
            const u64* hr = hbq + (((size_t)((t - 1) & 3) * 12 + g) << 12);
            u64 hu[16];
#pragma unroll
            for (int i = 0; i < 16; ++i) hu[i] = ld_h(hr + (mg0 + i) * 32 + bb);
            u64 gu[16];
            if (d > 0) {
                const u64* hg = hbq + (((size_t)(t & 3) * 12 + (g - 4)) << 12);
#pragma unroll
                for (int i = 0; i < 16; ++i) gu[i] = ld_h(hg + (mg0 + i) * 32 + bb);
            }
#pragma unroll
            for (int i = 0; i < 16; ++i) {
                const v2f* wp = (const v2f*)(s_whh + (m0 + i * 4) * 2);
                PKU64(hu[i], wp)
            }
            if (d > 0) {
#pragma unroll
                for (int i = 0; i < 16; ++i) {
                    const v2f* wp = (const v2f*)(s_wff + (m0 + i * 4) * 2);
                    PKU64(gu[i], wp)
                }
            }
        }

        const int par = t & 1;
        s_red[par][mseg][bb][0] = make_float4(acc0.x, acc0.y, acc1.x, acc1.y);
        s_red[par][mseg][bb][1] = make_float4(acc2.x, acc2.y, acc3.x, acc3.y);
        __syncthreads();          // B1: the ONLY barrier per step

        // ---- finalize: wave 0 only; waves 1-3 run ahead into t+1 ----
        if (tid < 64) {
            if (lane == 0) st_slot(rdfl + g * 64 + nt, t);   // reads for t done

            float4 s = s_red[par][0][fb][nh];
#pragma unroll
            for (int ms = 1; ms < MSEG; ++ms) {
                float4 r = s_red[par][ms][fb][nh];
                s.x += r.x; s.y += r.y; s.z += r.z; s.w += r.w;
            }
            float h0f, h1f, h2f, h3f;
            if (t == 0) {
                float4 v = *(const float4*)(h0 + (size_t)(d * BATCH + b0 + fb) * NH
                                            + n0 + nh * 4);
                h0f = v.x; h1f = v.y; h2f = v.z; h3f = v.w;
            } else {
                h0f = bflo((u32)prev);         h1f = bfhi((u32)prev);
                h2f = bflo((u32)(prev >> 32)); h3f = bfhi((u32)(prev >> 32));
            }
            float p0 = s.x + cbias[0] + xs * winp[0];
            float p1 = s.y + cbias[1] + xs * winp[1];
            float p2 = s.z + cbias[2] + xs * winp[2];
            float p3 = s.w + cbias[3] + xs * winp[3];
            float n0v = al[0] * h0f + lrelu(p0) * itau[0];
            float n1v = al[1] * h1f + lrelu(p1) * itau[1];
            float n2v = al[2] * h2f + lrelu(p2) * itau[2];
            float n3v = al[3] * h3f + lrelu(p3) * itau[3];
            u64 pk = pack4bf(n0v, n1v, n2v, n3v);

            // WAR guards (ring slack 3-4 steps; normally instant)
            if (t >= 3) {
                const int* p = rdfl + g * 64 + lane;
                while (!__all(ld_slot(p) >= t - 3)) __builtin_amdgcn_s_sleep(1);
            }
            if (d < DMOD - 1 && t >= 4) {
                const int* p = rdfl + (g + 4) * 64 + lane;
                while (!__all(ld_slot(p) >= t - 4)) __builtin_amdgcn_s_sleep(1);
            }

            u64* dst = hbq + (((size_t)(t & 3) * 12 + g) << 12)
                     + (size_t)(nt * 2 + nh) * 32 + fb;
            st_h(dst, pk);
            prev = pk;
            if (t == TSTEPS - 1) {
                *(float4*)(out + (size_t)(d * BATCH + b0 + fb) * NH + n0 + nh * 4)
                    = make_float4(n0v, n1v, n2v, n3v);
            }
            __threadfence_block();             // payload acked before tag
            if (lane == 0) {
                st_tag(tags + (size_t)(t & 3) * 768 + g * 64 + nt, (u32)(t + 1));
            }
        }
    }

    // ---- readout: wait for final-slab tags of own group, then heads ----
    if (tid < 64) {
        const u32* tf = tags + (size_t)((TSTEPS - 1) & 3) * 768 + g * 64 + tid;
        while (ld_tag(tf) != (u32)TSTEPS) __builtin_amdgcn_s_sleep(2);
    }
    __syncthreads();
    asm volatile("" ::: "memory");
    if (nt < CCLS && tid < BT) {
        const int c   = nt;
        const int row = b0 + tid;
        const u64* hf = hbq + (((size_t)((TSTEPS - 1) & 3) * 12 + g) << 12);
        const float4* wf = (const float4*)(W_fc + (size_t)(d * CCLS + c) * NH);
        float sacc = b_fc[d * CCLS + c];
        for (int q = 0; q < NH / 4; ++q) {
            u64 u = ld_h(hf + (size_t)q * 32 + tid);
            float4 w = wf[q];
            sacc += bflo((u32)u) * w.x + bfhi((u32)u) * w.y
                  + bflo((u32)(u >> 32)) * w.z + bfhi((u32)(u >> 32)) * w.w;
        }
        out[OUT2 + (size_t)(d * BATCH + row) * CCLS + c] = sacc;
    }
}

extern "C" void kernel_launch(void* const* d_in, const int* in_sizes, int n_in,
                              void* d_out, int out_size, void* d_ws, size_t ws_size,
                              hipStream_t stream) {
    const float* data = (const float*)d_in[0];
    const float* h0   = (const float*)d_in[1];
    const float* W_in = (const float*)d_in[2];
    const float* b_in = (const float*)d_in[3];
    const float* W_hh = (const float*)d_in[4];
    const float* b_hh = (const float*)d_in[5];
    const float* W_ff = (const float*)d_in[6];
    const float* b_ff = (const float*)d_in[7];
    const float* taus = (const float*)d_in[8];
    const float* W_fc = (const float*)d_in[9];
    const float* b_fc = (const float*)d_in[10];

    // no init needed: tag poison 0xAAAAAAAA != any expected value 1..512;
    // rdflag poison is negative (signed) = "not done". Store-only, no RMW.
    hipLaunchKernelGGL(rnn_v8, dim3(NBLK), dim3(NTHR), 0, stream,
                       data, h0, W_in, b_in, W_hh, b_hh, W_ff, b_ff,
                       taus, W_fc, b_fc, (float*)d_out, (int*)d_ws);
}